// Round 1
// baseline (304.250 us; speedup 1.0000x reference)
//
#include <hip/hip_runtime.h>

#define IN_DIM 128
#define OUT_DIM 64

// ---------------------------------------------------------------------------
// Phase 1: xw = x @ W.  One wave per row; lane = output column (OUT_DIM==64
// matches wave width exactly). W lives in LDS (128*64*4 = 32 KB); the k-loop
// read wl[k*64+lane] has stride-64 → 2-way bank aliasing, which is free on
// gfx950 (m136). x-row broadcast goes through a per-wave LDS buffer (intra-
// wave write->read, lockstep, no barrier needed).
// ---------------------------------------------------------------------------
__global__ __launch_bounds__(256) void gemm_xw(const float* __restrict__ x,
                                               const float* __restrict__ w,
                                               float* __restrict__ xw, int N) {
    __shared__ float wl[IN_DIM * OUT_DIM];   // 32 KB
    __shared__ float xb[4][IN_DIM];          // per-wave x-row staging
    {
        const float4* w4 = (const float4*)w;
        float4* wl4 = (float4*)wl;
        for (int i = threadIdx.x; i < IN_DIM * OUT_DIM / 4; i += 256)
            wl4[i] = w4[i];
    }
    __syncthreads();

    const int wave  = threadIdx.x >> 6;
    const int lane  = threadIdx.x & 63;
    const int gwave = blockIdx.x * 4 + wave;
    const int nwave = gridDim.x * 4;

    for (int row = gwave; row < N; row += nwave) {
        const float2* xr = (const float2*)(x + (size_t)row * IN_DIM);
        float2 xv = xr[lane];                 // coalesced 512 B wave read
        xb[wave][2 * lane]     = xv.x;        // intra-wave LDS broadcast
        xb[wave][2 * lane + 1] = xv.y;
        float acc = 0.f;
#pragma unroll 16
        for (int k = 0; k < IN_DIM; ++k)
            acc = fmaf(xb[wave][k], wl[k * OUT_DIM + lane], acc);
        xw[(size_t)row * OUT_DIM + lane] = acc;   // coalesced 256 B wave write
    }
}

// ---------------------------------------------------------------------------
// Phase 2: edge scatter.  Wave-per-edge; lane = column.  Gather is a
// contiguous 256 B wave read of xw[src]; scatter is 64 fp32 device-scope
// atomics into out[dst] (L2-resident, 12.8 MB target).
// ---------------------------------------------------------------------------
__global__ __launch_bounds__(256) void scatter_edges(
        const int* __restrict__ arow, const int* __restrict__ acol,
        const float* __restrict__ aval, const float* __restrict__ xw,
        float* __restrict__ out, int E) {
    const int lane = threadIdx.x & 63;
    int gw = (blockIdx.x * 256 + (int)threadIdx.x) >> 6;
    const int nw = (gridDim.x * 256) >> 6;
    for (int e = gw; e < E; e += nw) {
        const int   s = acol[e];
        const int   d = arow[e];
        const float v = aval[e];
        const float m = v * xw[(size_t)s * OUT_DIM + lane];
        atomicAdd(&out[(size_t)d * OUT_DIM + lane], m);
    }
}

// ---------------------------------------------------------------------------
// Phase 3: ReLU in place on d_out (runs after all atomics: same stream).
// ---------------------------------------------------------------------------
__global__ __launch_bounds__(256) void relu_inplace(float* __restrict__ o, int n4) {
    float4* p = (float4*)o;
    int i = blockIdx.x * 256 + threadIdx.x;
    const int stride = gridDim.x * 256;
    for (; i < n4; i += stride) {
        float4 v = p[i];
        v.x = v.x > 0.f ? v.x : 0.f;
        v.y = v.y > 0.f ? v.y : 0.f;
        v.z = v.z > 0.f ? v.z : 0.f;
        v.w = v.w > 0.f ? v.w : 0.f;
        p[i] = v;
    }
}

extern "C" void kernel_launch(void* const* d_in, const int* in_sizes, int n_in,
                              void* d_out, int out_size, void* d_ws, size_t ws_size,
                              hipStream_t stream) {
    const float* x    = (const float*)d_in[0];
    const float* w    = (const float*)d_in[1];
    const int*   arow = (const int*)d_in[2];
    const int*   acol = (const int*)d_in[3];
    const float* aval = (const float*)d_in[4];
    float*       out  = (float*)d_out;

    const int N = in_sizes[0] / IN_DIM;   // 50000
    const int E = in_sizes[2];            // 800000

    float* xw = (float*)d_ws;             // 50000*64*4 = 12.8 MB scratch

    // d_out is re-poisoned to 0xAA before every timed call — zero it.
    hipMemsetAsync(d_out, 0, (size_t)out_size * sizeof(float), stream);

    gemm_xw<<<800, 256, 0, stream>>>(x, w, xw, N);
    scatter_edges<<<4096, 256, 0, stream>>>(arow, acol, aval, xw, out, E);
    relu_inplace<<<2048, 256, 0, stream>>>(out, out_size / 4);
}